// Round 3
// baseline (42723.557 us; speedup 1.0000x reference)
//
#include <hip/hip_runtime.h>

#define HH 128
#define H 256
#define W 256
#define KK 51
#define HIMG 306
#define WIMG 306
#define CF 64
#define BB 4
#define HW (H * W)

// ---------------- upsample 2x bilinear (align_corners=True), one batch ----------------
__global__ void upsample_kernel(const float* __restrict__ x, float* __restrict__ up) {
    int idx = blockIdx.x * blockDim.x + threadIdx.x;   // [0, CF*H*W)
    int xx = idx & 255;
    int yy = (idx >> 8) & 255;
    int c = idx >> 16;
    const float s = 127.f / 255.f;
    float py = yy * s; int ly = (int)py; int hy = min(ly + 1, 127); float wy = py - (float)ly;
    float px = xx * s; int lx = (int)px; int hx = min(lx + 1, 127); float wx = px - (float)lx;
    const float* ip = x + (long)c * HH * HH;
    float v00 = ip[ly * HH + lx], v01 = ip[ly * HH + hx];
    float v10 = ip[hy * HH + lx], v11 = ip[hy * HH + hx];
    float a = v00 * (1.f - wy) + v10 * wy;
    float b = v01 * (1.f - wy) + v11 * wy;
    up[idx] = a * (1.f - wx) + b * wx;
}

// ---------------- register-tiled 3x3 conv + bias + relu, one batch ----------------
// in: [CIN,H,W], w: [51,CIN,3,3], out: [51,H,W]
// block: 256 = 64 lanes (4 x each, float4) x 4 waves (4 consecutive y)
// grid: (H/4, 17) ; 3 co per block (17*3 = 51 exact)
template <int CIN>
__global__ __launch_bounds__(256) void conv3x3_tiled(const float* __restrict__ in,
        const float* __restrict__ w, const float* __restrict__ bias,
        float* __restrict__ out) {
    __shared__ float sw[CIN][3][12];   // [ci][co_local][tap0..8 + pad], 16B-aligned rows
    const int lane = threadIdx.x & 63;
    const int wv   = threadIdx.x >> 6;
    const int y    = (blockIdx.x << 2) + wv;
    const int cob  = blockIdx.y * 3;

    for (int t = threadIdx.x; t < 3 * CIN * 9; t += 256) {
        int c = t / (CIN * 9);
        int r = t - c * (CIN * 9);
        sw[r / 9][c][r % 9] = w[(size_t)(cob + c) * CIN * 9 + r];
    }
    __syncthreads();

    const int x0 = lane << 2;
    float acc[3][4];
#pragma unroll
    for (int c = 0; c < 3; ++c) {
        float bv = bias[cob + c];
#pragma unroll
        for (int i = 0; i < 4; ++i) acc[c][i] = bv;
    }

    const float* ip = in + (size_t)y * W + x0;
#pragma unroll 2
    for (int ci = 0; ci < CIN; ++ci) {
        const float* p = ip + (size_t)ci * HW;
        float4 rm = (y > 0)     ? *(const float4*)(p - W) : float4{0.f, 0.f, 0.f, 0.f};
        float4 rc =               *(const float4*)(p);
        float4 rp = (y < H - 1) ? *(const float4*)(p + W) : float4{0.f, 0.f, 0.f, 0.f};

        float lm = __shfl_up(rm.w, 1);   if (lane == 0)  lm = 0.f;
        float lc = __shfl_up(rc.w, 1);   if (lane == 0)  lc = 0.f;
        float lp = __shfl_up(rp.w, 1);   if (lane == 0)  lp = 0.f;
        float hm = __shfl_down(rm.x, 1); if (lane == 63) hm = 0.f;
        float hc = __shfl_down(rc.x, 1); if (lane == 63) hc = 0.f;
        float hp = __shfl_down(rp.x, 1); if (lane == 63) hp = 0.f;

#pragma unroll
        for (int c = 0; c < 3; ++c) {
            const float* wp = &sw[ci][c][0];
            float w00 = wp[0], w01 = wp[1], w02 = wp[2];
            float w10 = wp[3], w11 = wp[4], w12 = wp[5];
            float w20 = wp[6], w21 = wp[7], w22 = wp[8];
            // ky = 0 (row y-1)
            acc[c][0] = fmaf(lm,   w00, fmaf(rm.x, w01, fmaf(rm.y, w02, acc[c][0])));
            acc[c][1] = fmaf(rm.x, w00, fmaf(rm.y, w01, fmaf(rm.z, w02, acc[c][1])));
            acc[c][2] = fmaf(rm.y, w00, fmaf(rm.z, w01, fmaf(rm.w, w02, acc[c][2])));
            acc[c][3] = fmaf(rm.z, w00, fmaf(rm.w, w01, fmaf(hm,   w02, acc[c][3])));
            // ky = 1 (row y)
            acc[c][0] = fmaf(lc,   w10, fmaf(rc.x, w11, fmaf(rc.y, w12, acc[c][0])));
            acc[c][1] = fmaf(rc.x, w10, fmaf(rc.y, w11, fmaf(rc.z, w12, acc[c][1])));
            acc[c][2] = fmaf(rc.y, w10, fmaf(rc.z, w11, fmaf(rc.w, w12, acc[c][2])));
            acc[c][3] = fmaf(rc.z, w10, fmaf(rc.w, w11, fmaf(hc,   w12, acc[c][3])));
            // ky = 2 (row y+1)
            acc[c][0] = fmaf(lp,   w20, fmaf(rp.x, w21, fmaf(rp.y, w22, acc[c][0])));
            acc[c][1] = fmaf(rp.x, w20, fmaf(rp.y, w21, fmaf(rp.z, w22, acc[c][1])));
            acc[c][2] = fmaf(rp.y, w20, fmaf(rp.z, w21, fmaf(rp.w, w22, acc[c][2])));
            acc[c][3] = fmaf(rp.z, w20, fmaf(rp.w, w21, fmaf(hp,   w22, acc[c][3])));
        }
    }

#pragma unroll
    for (int c = 0; c < 3; ++c) {
        float4 o;
        o.x = fmaxf(acc[c][0], 0.f);
        o.y = fmaxf(acc[c][1], 0.f);
        o.z = fmaxf(acc[c][2], 0.f);
        o.w = fmaxf(acc[c][3], 0.f);
        *(float4*)(out + ((size_t)(cob + c) * H + y) * W + x0) = o;
    }
}

// ---------------- separable 51x51 gather, LDS-staged rows, one batch ----------------
// img: [3,HIMG,WIMG] slice; kv/kh: [KK,H,W]; out: [3,H,W]
__global__ __launch_bounds__(256) void sepconv_lds(const float* __restrict__ img,
        const float* __restrict__ kv, const float* __restrict__ kh,
        float* __restrict__ out, int accum) {
    __shared__ float sr[KK][WIMG];     // 51 x 306 floats = 62.4 KB
    const int x = threadIdx.x;
    const int y = blockIdx.x;
    const int c = blockIdx.y;
    const float* ib = img + ((size_t)c * HIMG + y) * WIMG;
    for (int t = x; t < KK * WIMG; t += 256) {
        int i = t / WIMG, u = t - i * WIMG;
        sr[i][u] = ib[(size_t)i * WIMG + u];
    }
    const float* khp = kh + (size_t)y * W + x;
    const float* kvp = kv + (size_t)y * W + x;
    float khr[KK];
#pragma unroll
    for (int j = 0; j < KK; ++j) khr[j] = khp[(size_t)j * HW];
    __syncthreads();

    float acc = 0.f;
    for (int i = 0; i < KK; ++i) {
        float s = 0.f;
        const float* row = &sr[i][x];
#pragma unroll
        for (int j = 0; j < KK; ++j) s = fmaf(row[j], khr[j], s);
        acc = fmaf(s, kvp[(size_t)i * HW], acc);
    }
    size_t oi = ((size_t)c * H + y) * W + x;
    if (accum) out[oi] += acc;
    else       out[oi] = acc;
}

extern "C" void kernel_launch(void* const* d_in, const int* in_sizes, int n_in,
                              void* d_out, int out_size, void* d_ws, size_t ws_size,
                              hipStream_t stream) {
    const float* x  = (const float*)d_in[0];
    const float* i1 = (const float*)d_in[1];
    const float* i2 = (const float*)d_in[2];
    const float* W1 = (const float*)d_in[3];
    const float* B1 = (const float*)d_in[4];
    const float* W2 = (const float*)d_in[5];
    const float* B2 = (const float*)d_in[6];
    const float* W3 = (const float*)d_in[7];
    const float* B3 = (const float*)d_in[8];
    float* out = (float*)d_out;

    const size_t NUP1 = (size_t)CF * H * W;   // 16 MB
    const size_t NK1  = (size_t)KK * H * W;   // 12.75 MB
    float* ws   = (float*)d_ws;
    float* up   = ws;
    float* tmpA = up + NUP1;
    float* tmpB = tmpA + NK1;
    float* kvb  = tmpB + NK1;
    float* khb  = kvb + NK1;

    const size_t W1SZ  = (size_t)KK * CF * 9;
    const size_t W23SZ = (size_t)KK * KK * 9;

    for (int b = 0; b < BB; ++b) {
        upsample_kernel<<<NUP1 / 256, 256, 0, stream>>>(x + (size_t)b * CF * HH * HH, up);

        for (int p = 0; p < 2; ++p) {
            const float* img = (p ? i2 : i1) + (size_t)b * 3 * HIMG * WIMG;
            for (int h = 0; h < 2; ++h) {
                int k = 2 * p + h;
                float* dst = h ? khb : kvb;
                conv3x3_tiled<CF><<<dim3(H / 4, 17), 256, 0, stream>>>(up,   W1 + k * W1SZ,  B1 + k * KK, tmpA);
                conv3x3_tiled<KK><<<dim3(H / 4, 17), 256, 0, stream>>>(tmpA, W2 + k * W23SZ, B2 + k * KK, tmpB);
                conv3x3_tiled<KK><<<dim3(H / 4, 17), 256, 0, stream>>>(tmpB, W3 + k * W23SZ, B3 + k * KK, dst);
            }
            sepconv_lds<<<dim3(H, 3), 256, 0, stream>>>(img, kvb, khb,
                                                        out + (size_t)b * 3 * H * W, p);
        }
    }
}

// Round 4
// 811.845 us; speedup vs baseline: 52.6252x; 52.6252x over previous
//
#include <hip/hip_runtime.h>
#include <stdint.h>

#define HH 128
#define H 256
#define W 256
#define KK 51
#define HIMG 306
#define WIMG 306
#define CF 64
#define BB 4
#define HWN (H * W)
#define CHAIN ((size_t)HWN * 64)       // elems per [y][x][64] image

typedef short bhalf8 __attribute__((ext_vector_type(8)));
typedef float f32x4 __attribute__((ext_vector_type(4)));

__device__ inline uint16_t f2bf(float f) {
    uint32_t u = __builtin_bit_cast(uint32_t, f);
    u += 0x7FFF + ((u >> 16) & 1);
    return (uint16_t)(u >> 16);
}
__device__ inline float bf2f(uint16_t h) {
    uint32_t u = ((uint32_t)h) << 16;
    return __builtin_bit_cast(float, u);
}

// ---------------- upsample 2x bilinear (align_corners), one batch, fp32 [c][y][x] ----
__global__ void upsample_kernel(const float* __restrict__ x, float* __restrict__ up) {
    int idx = blockIdx.x * blockDim.x + threadIdx.x;   // [0, CF*H*W)
    int xx = idx & 255;
    int yy = (idx >> 8) & 255;
    int c = idx >> 16;
    const float s = 127.f / 255.f;
    float py = yy * s; int ly = (int)py; int hy = min(ly + 1, 127); float wy = py - (float)ly;
    float px = xx * s; int lx = (int)px; int hx = min(lx + 1, 127); float wx = px - (float)lx;
    const float* ip = x + (size_t)c * HH * HH;
    float v00 = ip[ly * HH + lx], v01 = ip[ly * HH + hx];
    float v10 = ip[hy * HH + lx], v11 = ip[hy * HH + hx];
    float a = v00 * (1.f - wy) + v10 * wy;
    float b = v01 * (1.f - wy) + v11 * wy;
    up[idx] = a * (1.f - wx) + b * wx;
}

// ---------------- transpose+cvt: [64][256][256] f32 -> [256][256][64] bf16 ----------
__global__ void transpose_cvt(const float* __restrict__ upf, uint16_t* __restrict__ upT) {
    __shared__ float tile[32][68];
    const int y = blockIdx.y;
    const int x0 = blockIdx.x * 32;
    const int t = threadIdx.x;
#pragma unroll
    for (int r = 0; r < 8; ++r) {
        int idx = t + r * 256;          // over 64c x 32x
        int xi = idx & 31, c = idx >> 5;
        tile[xi][c] = upf[(size_t)c * HWN + y * W + x0 + xi];
    }
    __syncthreads();
    int xj = t >> 3, cq = t & 7;
    uint32_t d[4];
#pragma unroll
    for (int q = 0; q < 4; ++q) {
        uint32_t lo = f2bf(tile[xj][cq * 8 + q * 2]);
        uint32_t hi = f2bf(tile[xj][cq * 8 + q * 2 + 1]);
        d[q] = lo | (hi << 16);
    }
    uint4 v = {d[0], d[1], d[2], d[3]};
    *(uint4*)(upT + ((size_t)y * W + x0 + xj) * 64 + cq * 8) = v;
}

// ---------------- weight prep: [4][51][CIN][3][3] f32 -> A-fragment order bf16 ------
// dst[k][tap][m(4)][cihalf(2)][lane(64)][8] ; co = m*16+(lane&15), ci = cihalf*32+(lane>>4)*8+e
__global__ void wprep(const float* __restrict__ wsrc, uint16_t* __restrict__ wdst, int cin_act) {
    int g = blockIdx.x * 256 + threadIdx.x;    // one per 16B group: 4*9*4*2*64 = 18432
    if (g >= 4 * 9 * 4 * 2 * 64) return;
    int lane = g & 63;
    int q = g >> 6;
    int ch = q & 1; q >>= 1;
    int m = q & 3; q >>= 2;
    int tap = q % 9;
    int k = q / 9;
    int co = m * 16 + (lane & 15);
    int ci0 = ch * 32 + (lane >> 4) * 8;
    uint32_t d[4];
#pragma unroll
    for (int p = 0; p < 4; ++p) {
        uint32_t w2[2];
#pragma unroll
        for (int e = 0; e < 2; ++e) {
            int ci = ci0 + p * 2 + e;
            float v = 0.f;
            if (co < KK && ci < cin_act)
                v = wsrc[((size_t)(k * KK + co) * cin_act + ci) * 9 + tap];
            w2[e] = f2bf(v);
        }
        d[p] = w2[0] | (w2[1] << 16);
    }
    uint4 v = {d[0], d[1], d[2], d[3]};
    *(uint4*)(wdst + (size_t)g * 8) = v;
}

// ---------------- MFMA conv 3x3 + bias + relu --------------------------------------
// in/out: [y][x][64] bf16 ; block = 4 waves (y0..y0+3) x 128 px ; grid (64, 2, NZ)
__global__ __launch_bounds__(256, 2)
void conv_mfma(const uint16_t* __restrict__ in, const uint16_t* __restrict__ wp,
               const float* __restrict__ bias, uint16_t* __restrict__ out,
               size_t in_kstride, int kbase) {
    const int z = blockIdx.z;
    const int k = kbase + z;
    in  += (size_t)z * in_kstride;
    out += (size_t)z * CHAIN;
    const int y0 = blockIdx.x * 4;
    const int x0 = blockIdx.y * 128;
    const int tid = threadIdx.x;
    const int lane = tid & 63;
    const int wv = tid >> 6;
    const int y = y0 + wv;

    __shared__ uint4 lds[6 * 130 * 4];   // [row 6][xl 130][slot 4] 16B chunks, 49.9 KB

    f32x4 acc[4][8];
#pragma unroll
    for (int m = 0; m < 4; ++m)
#pragma unroll
        for (int n = 0; n < 8; ++n)
            acc[m][n] = (f32x4){0.f, 0.f, 0.f, 0.f};

    for (int chf = 0; chf < 2; ++chf) {
        if (chf) __syncthreads();
        // stage 6 rows x 130 xl x 4 chunks (ci chf*32 .. +32), zero-padded borders
        for (int task = tid; task < 6 * 130 * 4; task += 256) {
            int chunk = task & 3;
            int xl = (task >> 2) % 130;
            int r = (task >> 2) / 130;
            int yg = y0 - 1 + r;
            int xg = x0 + xl - 1;
            uint4 v = {0u, 0u, 0u, 0u};
            if ((unsigned)yg < H && (unsigned)xg < W)
                v = *(const uint4*)(in + (((size_t)yg * W + xg) * 64 + chf * 32 + chunk * 8));
            int slot = chunk ^ ((xl >> 1) & 3);
            lds[(r * 130 + xl) * 4 + slot] = v;
        }
        __syncthreads();

#pragma unroll
        for (int tap = 0; tap < 9; ++tap) {
            const int ky = tap / 3, kx = tap % 3;
            bhalf8 afr[4];
#pragma unroll
            for (int m = 0; m < 4; ++m)
                afr[m] = *(const bhalf8*)(wp + ((((size_t)(k * 9 + tap) * 4 + m) * 2 + chf) * 64 + lane) * 8);
            const int rrow = wv + ky;
            const int chunk = lane >> 4;
#pragma unroll
            for (int n = 0; n < 8; ++n) {
                int xl = n * 16 + (lane & 15) + kx;
                int slot = chunk ^ ((xl >> 1) & 3);
                bhalf8 bfr = *(const bhalf8*)&lds[(rrow * 130 + xl) * 4 + slot];
#pragma unroll
                for (int m = 0; m < 4; ++m)
                    acc[m][n] = __builtin_amdgcn_mfma_f32_16x16x32_bf16(afr[m], bfr, acc[m][n], 0, 0, 0);
            }
        }
    }

    // epilogue: bias + relu + bf16 pack; D: col(x)=lane&15, row(co)=(lane>>4)*4+r
    const int colx = lane & 15;
    const int r4 = lane >> 4;
#pragma unroll
    for (int m = 0; m < 4; ++m) {
        float bv[4];
#pragma unroll
        for (int r = 0; r < 4; ++r) {
            int co = m * 16 + r4 * 4 + r;
            bv[r] = (co < KK) ? bias[k * KK + co] : 0.f;
        }
#pragma unroll
        for (int n = 0; n < 8; ++n) {
            int xg = x0 + n * 16 + colx;
            uint32_t pk[2];
#pragma unroll
            for (int h = 0; h < 2; ++h) {
                uint32_t lo = f2bf(fmaxf(acc[m][n][h * 2]     + bv[h * 2],     0.f));
                uint32_t hi = f2bf(fmaxf(acc[m][n][h * 2 + 1] + bv[h * 2 + 1], 0.f));
                pk[h] = lo | (hi << 16);
            }
            uint2 st = {pk[0], pk[1]};
            *(uint2*)(out + (((size_t)y * W + xg) * 64 + m * 16 + r4 * 4)) = st;
        }
    }
}

// ---------------- separable 51x51 gather, one batch --------------------------------
// img fp32 [3][306][306]; kvT/khT bf16 [y][x][64]; out fp32 [3][H][W]
__global__ __launch_bounds__(256)
void sepconv2(const float* __restrict__ img, const uint16_t* __restrict__ kvT,
              const uint16_t* __restrict__ khT, float* __restrict__ out, int accum) {
    __shared__ float sr[KK][WIMG + 1];
    const int x = threadIdx.x;
    const int y = blockIdx.x;
    const int c = blockIdx.y;
    const float* ib = img + ((size_t)c * HIMG + y) * WIMG;
    for (int t = x; t < KK * WIMG; t += 256) {
        int i = t / WIMG, u = t - i * WIMG;
        sr[i][u] = ib[(size_t)i * WIMG + u];
    }
    const uint16_t* kp = khT + ((size_t)y * W + x) * 64;
    const uint16_t* vp = kvT + ((size_t)y * W + x) * 64;
    float khr[KK];
#pragma unroll
    for (int j = 0; j < KK; ++j) khr[j] = bf2f(kp[j]);
    __syncthreads();

    float accv = 0.f;
    for (int i = 0; i < KK; ++i) {
        float s = 0.f;
        const float* row = &sr[i][x];
#pragma unroll
        for (int j = 0; j < KK; ++j) s = fmaf(row[j], khr[j], s);
        accv = fmaf(s, bf2f(vp[i]), accv);
    }
    size_t oi = ((size_t)c * H + y) * W + x;
    if (accum) out[oi] += accv;
    else       out[oi] = accv;
}

extern "C" void kernel_launch(void* const* d_in, const int* in_sizes, int n_in,
                              void* d_out, int out_size, void* d_ws, size_t ws_size,
                              hipStream_t stream) {
    const float* x  = (const float*)d_in[0];
    const float* i1 = (const float*)d_in[1];
    const float* i2 = (const float*)d_in[2];
    const float* W1 = (const float*)d_in[3];
    const float* B1 = (const float*)d_in[4];
    const float* W2 = (const float*)d_in[5];
    const float* B2 = (const float*)d_in[6];
    const float* W3 = (const float*)d_in[7];
    const float* B3 = (const float*)d_in[8];
    float* out = (float*)d_out;

    char* wsb = (char*)d_ws;
    const size_t IMGB = CHAIN * 2;              // 8,388,608 B per [y][x][64] bf16 image
    const size_t WPN = 4 * 9 * 4 * 2 * 64 * 8;  // 147,456 elems per layer
    const size_t FULL_NEED = 3 * 4 * IMGB + IMGB + 3 * WPN * 2;  // ~110 MB
    const bool full = ws_size >= FULL_NEED;

    if (full) {
        // [r1 4img][r2 4img (upf fp32 aliases first 16.78MB)][r3 4img][upT 1img][wp x3]
        uint16_t* r1  = (uint16_t*)wsb;
        char*     r2b = wsb + 4 * IMGB;
        uint16_t* r2  = (uint16_t*)r2b;
        float*    upf = (float*)r2b;
        uint16_t* r3  = (uint16_t*)(wsb + 8 * IMGB);
        uint16_t* upT = (uint16_t*)(wsb + 12 * IMGB);
        uint16_t* wp1 = (uint16_t*)(wsb + 13 * IMGB);
        uint16_t* wp2 = wp1 + WPN;
        uint16_t* wp3 = wp2 + WPN;

        wprep<<<72, 256, 0, stream>>>(W1, wp1, CF);
        wprep<<<72, 256, 0, stream>>>(W2, wp2, KK);
        wprep<<<72, 256, 0, stream>>>(W3, wp3, KK);

        for (int b = 0; b < BB; ++b) {
            upsample_kernel<<<(CF * HWN) / 256, 256, 0, stream>>>(x + (size_t)b * CF * HH * HH, upf);
            transpose_cvt<<<dim3(W / 32, H), 256, 0, stream>>>(upf, upT);
            conv_mfma<<<dim3(64, 2, 4), 256, 0, stream>>>(upT, wp1, B1, r1, 0, 0);
            conv_mfma<<<dim3(64, 2, 4), 256, 0, stream>>>(r1, wp2, B2, r2, CHAIN, 0);
            conv_mfma<<<dim3(64, 2, 4), 256, 0, stream>>>(r2, wp3, B3, r3, CHAIN, 0);
            for (int p = 0; p < 2; ++p) {
                const float* img = (p ? i2 : i1) + (size_t)b * 3 * HIMG * WIMG;
                sepconv2<<<dim3(H, 3), 256, 0, stream>>>(img, r3 + (size_t)(2 * p) * CHAIN,
                                                         r3 + (size_t)(2 * p + 1) * CHAIN,
                                                         out + (size_t)b * 3 * HWN, p);
            }
        }
    } else {
        // [upf fp32 = t2 2img][upT 1img][t1 2img][t3 2img][wp x3]  (~59.8 MB)
        float*    upf = (float*)wsb;
        uint16_t* t2  = (uint16_t*)wsb;
        uint16_t* upT = (uint16_t*)(wsb + 2 * IMGB);
        uint16_t* t1  = (uint16_t*)(wsb + 3 * IMGB);
        uint16_t* t3  = (uint16_t*)(wsb + 5 * IMGB);
        uint16_t* wp1 = (uint16_t*)(wsb + 7 * IMGB);
        uint16_t* wp2 = wp1 + WPN;
        uint16_t* wp3 = wp2 + WPN;

        wprep<<<72, 256, 0, stream>>>(W1, wp1, CF);
        wprep<<<72, 256, 0, stream>>>(W2, wp2, KK);
        wprep<<<72, 256, 0, stream>>>(W3, wp3, KK);

        for (int b = 0; b < BB; ++b) {
            upsample_kernel<<<(CF * HWN) / 256, 256, 0, stream>>>(x + (size_t)b * CF * HH * HH, upf);
            transpose_cvt<<<dim3(W / 32, H), 256, 0, stream>>>(upf, upT);
            for (int p = 0; p < 2; ++p) {
                const float* img = (p ? i2 : i1) + (size_t)b * 3 * HIMG * WIMG;
                conv_mfma<<<dim3(64, 2, 2), 256, 0, stream>>>(upT, wp1, B1, t1, 0, 2 * p);
                conv_mfma<<<dim3(64, 2, 2), 256, 0, stream>>>(t1, wp2, B2, t2, CHAIN, 2 * p);
                conv_mfma<<<dim3(64, 2, 2), 256, 0, stream>>>(t2, wp3, B3, t3, CHAIN, 2 * p);
                sepconv2<<<dim3(H, 3), 256, 0, stream>>>(img, t3, t3 + CHAIN,
                                                         out + (size_t)b * 3 * HWN, p);
            }
        }
    }
}

// Round 5
// 651.596 us; speedup vs baseline: 65.5675x; 1.2459x over previous
//
#include <hip/hip_runtime.h>
#include <stdint.h>

#define HH 128
#define H 256
#define W 256
#define KK 51
#define HIMG 306
#define WIMG 306
#define IMW 312                         // padded bf16 img row (16B-aligned)
#define CF 64
#define BB 4
#define HWN (H * W)
#define CHAIN ((size_t)HWN * 64)        // elems per [y][x][64] image

typedef short bhalf8 __attribute__((ext_vector_type(8)));
typedef float f32x4 __attribute__((ext_vector_type(4)));

__device__ inline uint16_t f2bf(float f) {
    uint32_t u = __builtin_bit_cast(uint32_t, f);
    u += 0x7FFF + ((u >> 16) & 1);
    return (uint16_t)(u >> 16);
}
__device__ inline float bf2f(uint16_t h) {
    uint32_t u = ((uint32_t)h) << 16;
    return __builtin_bit_cast(float, u);
}

// ---------------- fused upsample 2x (align_corners) + cvt: x[64][128][128] f32 -> upT [y][x][64] bf16
__global__ __launch_bounds__(256) void upsample_cvt(const float* __restrict__ xin,
                                                    uint16_t* __restrict__ upT) {
    __shared__ float SU[2][64][19];
    const int y = blockIdx.x, x0 = blockIdx.y * 32;
    const float s = 127.f / 255.f;
    float py = y * s; int ly = (int)py; int hy = min(ly + 1, 127); float wy = py - (float)ly;
    int lx0 = (int)(x0 * s);
    for (int t = threadIdx.x; t < 2 * 64 * 18; t += 256) {
        int col = t % 18; int c = (t / 18) & 63; int row = t / (18 * 64);
        int sy = row ? hy : ly;
        int sx = min(lx0 + col, 127);
        SU[row][c][col] = xin[((size_t)c * 128 + sy) * 128 + sx];
    }
    __syncthreads();
    const int xl = threadIdx.x & 31, cg = threadIdx.x >> 5;
    const int x = x0 + xl;
    float px = x * s; int lx = (int)px; float wx = px - (float)lx;
    int lxl = lx - lx0;
    int hxl = min(lx + 1, 127) - lx0;
    uint32_t d[4];
#pragma unroll
    for (int q4 = 0; q4 < 4; ++q4) {
        uint32_t two[2];
#pragma unroll
        for (int e = 0; e < 2; ++e) {
            int c = cg * 8 + q4 * 2 + e;
            float v00 = SU[0][c][lxl], v01 = SU[0][c][hxl];
            float v10 = SU[1][c][lxl], v11 = SU[1][c][hxl];
            float a = v00 * (1.f - wy) + v10 * wy;
            float b = v01 * (1.f - wy) + v11 * wy;
            two[e] = f2bf(a * (1.f - wx) + b * wx);
        }
        d[q4] = two[0] | (two[1] << 16);
    }
    uint4 v = {d[0], d[1], d[2], d[3]};
    *(uint4*)(upT + ((size_t)y * W + x) * 64 + cg * 8) = v;
}

// ---------------- img cvt: i1,i2 [4][3][306][306] f32 -> imgb [2][4][3][306][312] bf16 (pad=0)
__global__ void img_cvt(const float* __restrict__ i1, const float* __restrict__ i2,
                        uint16_t* __restrict__ dst) {
    int task = blockIdx.x * 256 + threadIdx.x;      // 7344 rows x 39 chunks
    if (task >= 7344 * 39) return;
    int ch8 = task % 39, row = task / 39;
    int u0 = ch8 * 8;
    int img = row / 3672;
    int r = row - img * 3672;
    const float* src = (img ? i2 : i1) + (size_t)r * WIMG;
    uint32_t d[4];
#pragma unroll
    for (int p = 0; p < 4; ++p) {
        int u = u0 + p * 2;
        uint32_t lo = (u < WIMG) ? f2bf(src[u]) : 0u;
        uint32_t hi = (u + 1 < WIMG) ? f2bf(src[u + 1]) : 0u;
        d[p] = lo | (hi << 16);
    }
    uint4 v = {d[0], d[1], d[2], d[3]};
    *(uint4*)(dst + (size_t)row * IMW + u0) = v;
}

// ---------------- weight prep: [4][51][CIN][3][3] f32 -> A-fragment order bf16 ------
__global__ void wprep(const float* __restrict__ wsrc, uint16_t* __restrict__ wdst, int cin_act) {
    int g = blockIdx.x * 256 + threadIdx.x;    // one per 16B group: 4*9*4*2*64 = 18432
    if (g >= 4 * 9 * 4 * 2 * 64) return;
    int lane = g & 63;
    int q = g >> 6;
    int ch = q & 1; q >>= 1;
    int m = q & 3; q >>= 2;
    int tap = q % 9;
    int k = q / 9;
    int co = m * 16 + (lane & 15);
    int ci0 = ch * 32 + (lane >> 4) * 8;
    uint32_t d[4];
#pragma unroll
    for (int p = 0; p < 4; ++p) {
        uint32_t w2[2];
#pragma unroll
        for (int e = 0; e < 2; ++e) {
            int ci = ci0 + p * 2 + e;
            float v = 0.f;
            if (co < KK && ci < cin_act)
                v = wsrc[((size_t)(k * KK + co) * cin_act + ci) * 9 + tap];
            w2[e] = f2bf(v);
        }
        d[p] = w2[0] | (w2[1] << 16);
    }
    uint4 v = {d[0], d[1], d[2], d[3]};
    *(uint4*)(wdst + (size_t)g * 8) = v;
}

// ---------------- MFMA conv 3x3 + bias + relu (unchanged from round 4) --------------
__global__ __launch_bounds__(256, 2)
void conv_mfma(const uint16_t* __restrict__ in, const uint16_t* __restrict__ wp,
               const float* __restrict__ bias, uint16_t* __restrict__ out,
               size_t in_kstride, int kbase) {
    const int z = blockIdx.z;
    const int k = kbase + z;
    in  += (size_t)z * in_kstride;
    out += (size_t)z * CHAIN;
    const int y0 = blockIdx.x * 4;
    const int x0 = blockIdx.y * 128;
    const int tid = threadIdx.x;
    const int lane = tid & 63;
    const int wv = tid >> 6;
    const int y = y0 + wv;

    __shared__ uint4 lds[6 * 130 * 4];

    f32x4 acc[4][8];
#pragma unroll
    for (int m = 0; m < 4; ++m)
#pragma unroll
        for (int n = 0; n < 8; ++n)
            acc[m][n] = (f32x4){0.f, 0.f, 0.f, 0.f};

    for (int chf = 0; chf < 2; ++chf) {
        if (chf) __syncthreads();
        for (int task = tid; task < 6 * 130 * 4; task += 256) {
            int chunk = task & 3;
            int xl = (task >> 2) % 130;
            int r = (task >> 2) / 130;
            int yg = y0 - 1 + r;
            int xg = x0 + xl - 1;
            uint4 v = {0u, 0u, 0u, 0u};
            if ((unsigned)yg < H && (unsigned)xg < W)
                v = *(const uint4*)(in + (((size_t)yg * W + xg) * 64 + chf * 32 + chunk * 8));
            int slot = chunk ^ ((xl >> 1) & 3);
            lds[(r * 130 + xl) * 4 + slot] = v;
        }
        __syncthreads();

#pragma unroll
        for (int tap = 0; tap < 9; ++tap) {
            const int ky = tap / 3, kx = tap % 3;
            bhalf8 afr[4];
#pragma unroll
            for (int m = 0; m < 4; ++m)
                afr[m] = *(const bhalf8*)(wp + ((((size_t)(k * 9 + tap) * 4 + m) * 2 + chf) * 64 + lane) * 8);
            const int rrow = wv + ky;
            const int chunk = lane >> 4;
#pragma unroll
            for (int n = 0; n < 8; ++n) {
                int xl = n * 16 + (lane & 15) + kx;
                int slot = chunk ^ ((xl >> 1) & 3);
                bhalf8 bfr = *(const bhalf8*)&lds[(rrow * 130 + xl) * 4 + slot];
#pragma unroll
                for (int m = 0; m < 4; ++m)
                    acc[m][n] = __builtin_amdgcn_mfma_f32_16x16x32_bf16(afr[m], bfr, acc[m][n], 0, 0, 0);
            }
        }
    }

    const int colx = lane & 15;
    const int r4 = lane >> 4;
#pragma unroll
    for (int m = 0; m < 4; ++m) {
        float bv[4];
#pragma unroll
        for (int r = 0; r < 4; ++r) {
            int co = m * 16 + r4 * 4 + r;
            bv[r] = (co < KK) ? bias[k * KK + co] : 0.f;
        }
#pragma unroll
        for (int n = 0; n < 8; ++n) {
            int xg = x0 + n * 16 + colx;
            uint32_t pk[2];
#pragma unroll
            for (int h = 0; h < 2; ++h) {
                uint32_t lo = f2bf(fmaxf(acc[m][n][h * 2]     + bv[h * 2],     0.f));
                uint32_t hi = f2bf(fmaxf(acc[m][n][h * 2 + 1] + bv[h * 2 + 1], 0.f));
                pk[h] = lo | (hi << 16);
            }
            uint2 st = {pk[0], pk[1]};
            *(uint2*)(out + (((size_t)y * W + xg) * 64 + m * 16 + r4 * 4)) = st;
        }
    }
}

// ---------------- sepconv via MFMA band-matmul -------------------------------------
// V[x,u] = sum_i kv[i,y,x]*img[y+i,u] (K=64, kv[i>=51]==0), then out[x] = sum_j V[x,x+j]*kh[j,y,x]
// block = (y, c), 256 thr = 4 waves x 4 xtiles of 16 x each.
__global__ __launch_bounds__(256, 2)
void sepconv3(const uint16_t* __restrict__ imgb,   // [3][306][312] bf16 base for (img,b)
              const uint16_t* __restrict__ kvT, const uint16_t* __restrict__ khT,
              float* __restrict__ out, int accum) {
    __shared__ uint4 SB[320 * 8];                  // [u 320][ichunk 8 xor-swizzled], 40960 B
    __shared__ float SC[4][16 * 83];               // per-wave C band [x16][u_rel 83], 21248 B
    const int y = blockIdx.x, c = blockIdx.y;
    const int tid = threadIdx.x, lane = tid & 63, wv = tid >> 6;
    const uint16_t* img = imgb + (size_t)c * HIMG * IMW;

    // stage B transposed with chunk swizzle; zero-fill i=51..63 and u>=312
    for (int task = tid; task < 40 * 64; task += 256) {
        int i = task & 63;                          // = lane (wave-wide 0..63)
        int u0 = (task >> 6) * 8;
        uint4 v = {0u, 0u, 0u, 0u};
        if (i <= 50 && u0 < IMW)
            v = *(const uint4*)(img + (size_t)(y + i) * IMW + u0);
        ushort* vs = (ushort*)&v;
#pragma unroll
        for (int e = 0; e < 8; ++e) {
            int u = u0 + e;
            *((ushort*)SB + u * 64 + (((i >> 3) ^ (u & 7)) << 3) + (i & 7)) = vs[e];
        }
    }
    __syncthreads();

    const int l4 = lane & 15, g = lane >> 4;
    for (int xt = 0; xt < 4; ++xt) {
        const int x0 = (wv * 4 + xt) * 16;
        const int xpix = x0 + l4;
        bhalf8 a0 = *(const bhalf8*)(kvT + ((size_t)y * W + xpix) * 64 + g * 8);
        bhalf8 a1 = *(const bhalf8*)(kvT + ((size_t)y * W + xpix) * 64 + 32 + g * 8);
        f32x4 acc[5];
#pragma unroll
        for (int nt = 0; nt < 5; ++nt) acc[nt] = (f32x4){0.f, 0.f, 0.f, 0.f};
#pragma unroll
        for (int nt = 0; nt < 5; ++nt) {
            int u = x0 + nt * 16 + l4;
            bhalf8 b0 = *(const bhalf8*)((ushort*)SB + u * 64 + ((g ^ (u & 7)) << 3));
            acc[nt] = __builtin_amdgcn_mfma_f32_16x16x32_bf16(a0, b0, acc[nt], 0, 0, 0);
            bhalf8 b1 = *(const bhalf8*)((ushort*)SB + u * 64 + (((4 + g) ^ (u & 7)) << 3));
            acc[nt] = __builtin_amdgcn_mfma_f32_16x16x32_bf16(a1, b1, acc[nt], 0, 0, 0);
        }
        // spill band to per-wave LDS: row = x-local (g*4+r), col = u_rel
#pragma unroll
        for (int nt = 0; nt < 5; ++nt)
#pragma unroll
            for (int r = 0; r < 4; ++r)
                SC[wv][(g * 4 + r) * 83 + nt * 16 + l4] = acc[nt][r];

        // horizontal: lane (xl=l4, jgroup=g of 13 taps), reduce over 4 groups
        const uint16_t* khp = khT + ((size_t)y * W + xpix) * 64;
        float partial = 0.f;
#pragma unroll
        for (int jj = 0; jj < 13; ++jj) {
            int j = g * 13 + jj;
            if (j < KK)
                partial = fmaf(SC[wv][l4 * 83 + l4 + j], bf2f(khp[j]), partial);
        }
        partial += __shfl_xor(partial, 16);
        partial += __shfl_xor(partial, 32);
        if (g == 0) {
            size_t oi = ((size_t)c * H + y) * W + xpix;
            if (accum) out[oi] += partial;
            else       out[oi] = partial;
        }
    }
}

extern "C" void kernel_launch(void* const* d_in, const int* in_sizes, int n_in,
                              void* d_out, int out_size, void* d_ws, size_t ws_size,
                              hipStream_t stream) {
    const float* x  = (const float*)d_in[0];
    const float* i1 = (const float*)d_in[1];
    const float* i2 = (const float*)d_in[2];
    const float* W1 = (const float*)d_in[3];
    const float* B1 = (const float*)d_in[4];
    const float* W2 = (const float*)d_in[5];
    const float* B2 = (const float*)d_in[6];
    const float* W3 = (const float*)d_in[7];
    const float* B3 = (const float*)d_in[8];
    float* out = (float*)d_out;

    char* wsb = (char*)d_ws;
    const size_t IMGB = CHAIN * 2;                    // 8,388,608 B
    const size_t WPN  = 4 * 9 * 4 * 2 * 64 * 8;       // elems per wp layer
    const size_t WPB  = WPN * 2;
    const size_t IMGBYTES = (size_t)2 * 4 * 3 * HIMG * IMW * 2;   // 4,582,656 B
    const size_t FULL_NEED = 13 * IMGB + 3 * WPB + IMGBYTES;      // ~114.5 MB
    const bool full = ws_size >= FULL_NEED;
    const size_t W1SZ  = (size_t)KK * CF * 9;
    const size_t W23SZ = (size_t)KK * KK * 9;
    const int IMG_CVT_BLOCKS = (7344 * 39 + 255) / 256;

    if (full) {
        uint16_t* r1   = (uint16_t*)wsb;
        uint16_t* r2   = (uint16_t*)(wsb + 4 * IMGB);
        uint16_t* r3   = (uint16_t*)(wsb + 8 * IMGB);
        uint16_t* upT  = (uint16_t*)(wsb + 12 * IMGB);
        uint16_t* wp1  = (uint16_t*)(wsb + 13 * IMGB);
        uint16_t* wp2  = wp1 + WPN;
        uint16_t* wp3  = wp2 + WPN;
        uint16_t* imgb = wp3 + WPN;

        wprep<<<72, 256, 0, stream>>>(W1, wp1, CF);
        wprep<<<72, 256, 0, stream>>>(W2, wp2, KK);
        wprep<<<72, 256, 0, stream>>>(W3, wp3, KK);
        img_cvt<<<IMG_CVT_BLOCKS, 256, 0, stream>>>(i1, i2, imgb);

        for (int b = 0; b < BB; ++b) {
            upsample_cvt<<<dim3(H, 8), 256, 0, stream>>>(x + (size_t)b * CF * HH * HH, upT);
            conv_mfma<<<dim3(64, 2, 4), 256, 0, stream>>>(upT, wp1, B1, r1, 0, 0);
            conv_mfma<<<dim3(64, 2, 4), 256, 0, stream>>>(r1, wp2, B2, r2, CHAIN, 0);
            conv_mfma<<<dim3(64, 2, 4), 256, 0, stream>>>(r2, wp3, B3, r3, CHAIN, 0);
            for (int p = 0; p < 2; ++p) {
                const uint16_t* ib = imgb + ((size_t)(p * 12 + b * 3) * HIMG) * IMW;
                sepconv3<<<dim3(H, 3), 256, 0, stream>>>(ib,
                        r3 + (size_t)(2 * p) * CHAIN, r3 + (size_t)(2 * p + 1) * CHAIN,
                        out + (size_t)b * 3 * HWN, p);
            }
        }
    } else {
        uint16_t* upT  = (uint16_t*)wsb;
        uint16_t* t1   = (uint16_t*)(wsb + 1 * IMGB);
        uint16_t* t2   = (uint16_t*)(wsb + 3 * IMGB);
        uint16_t* t3   = (uint16_t*)(wsb + 5 * IMGB);
        uint16_t* wp1  = (uint16_t*)(wsb + 7 * IMGB);
        uint16_t* wp2  = wp1 + WPN;
        uint16_t* wp3  = wp2 + WPN;
        uint16_t* imgb = wp3 + WPN;

        wprep<<<72, 256, 0, stream>>>(W1, wp1, CF);
        wprep<<<72, 256, 0, stream>>>(W2, wp2, KK);
        wprep<<<72, 256, 0, stream>>>(W3, wp3, KK);
        img_cvt<<<IMG_CVT_BLOCKS, 256, 0, stream>>>(i1, i2, imgb);

        for (int b = 0; b < BB; ++b) {
            upsample_cvt<<<dim3(H, 8), 256, 0, stream>>>(x + (size_t)b * CF * HH * HH, upT);
            for (int p = 0; p < 2; ++p) {
                conv_mfma<<<dim3(64, 2, 2), 256, 0, stream>>>(upT, wp1, B1, t1, 0, 2 * p);
                conv_mfma<<<dim3(64, 2, 2), 256, 0, stream>>>(t1, wp2, B2, t2, CHAIN, 2 * p);
                conv_mfma<<<dim3(64, 2, 2), 256, 0, stream>>>(t2, wp3, B3, t3, CHAIN, 2 * p);
                const uint16_t* ib = imgb + ((size_t)(p * 12 + b * 3) * HIMG) * IMW;
                sepconv3<<<dim3(H, 3), 256, 0, stream>>>(ib, t3, t3 + CHAIN,
                        out + (size_t)b * 3 * HWN, p);
            }
        }
    }
}

// Round 6
// 590.657 us; speedup vs baseline: 72.3323x; 1.1032x over previous
//
#include <hip/hip_runtime.h>
#include <stdint.h>

#define HH 128
#define H 256
#define W 256
#define KK 51
#define HIMG 306
#define WIMG 306
#define IMW 312                         // padded bf16 img row (16B-aligned)
#define CF 64
#define BB 4
#define HWN (H * W)
#define CHAIN ((size_t)HWN * 64)        // elems per [y][x][64] image

typedef short bhalf8 __attribute__((ext_vector_type(8)));
typedef float f32x4 __attribute__((ext_vector_type(4)));

__device__ inline uint16_t f2bf(float f) {
    uint32_t u = __builtin_bit_cast(uint32_t, f);
    u += 0x7FFF + ((u >> 16) & 1);
    return (uint16_t)(u >> 16);
}
__device__ inline float bf2f(uint16_t h) {
    uint32_t u = ((uint32_t)h) << 16;
    return __builtin_bit_cast(float, u);
}

// ---------------- fused upsample 2x (align_corners) + cvt: x[64][128][128] f32 -> upT [y][x][64] bf16
__global__ __launch_bounds__(256) void upsample_cvt(const float* __restrict__ xin,
                                                    uint16_t* __restrict__ upT) {
    __shared__ float SU[2][64][19];
    const int y = blockIdx.x, x0 = blockIdx.y * 32;
    const float s = 127.f / 255.f;
    float py = y * s; int ly = (int)py; int hy = min(ly + 1, 127); float wy = py - (float)ly;
    int lx0 = (int)(x0 * s);
    for (int t = threadIdx.x; t < 2 * 64 * 18; t += 256) {
        int col = t % 18; int c = (t / 18) & 63; int row = t / (18 * 64);
        int sy = row ? hy : ly;
        int sx = min(lx0 + col, 127);
        SU[row][c][col] = xin[((size_t)c * 128 + sy) * 128 + sx];
    }
    __syncthreads();
    const int xl = threadIdx.x & 31, cg = threadIdx.x >> 5;
    const int x = x0 + xl;
    float px = x * s; int lx = (int)px; float wx = px - (float)lx;
    int lxl = lx - lx0;
    int hxl = min(lx + 1, 127) - lx0;
    uint32_t d[4];
#pragma unroll
    for (int q4 = 0; q4 < 4; ++q4) {
        uint32_t two[2];
#pragma unroll
        for (int e = 0; e < 2; ++e) {
            int c = cg * 8 + q4 * 2 + e;
            float v00 = SU[0][c][lxl], v01 = SU[0][c][hxl];
            float v10 = SU[1][c][lxl], v11 = SU[1][c][hxl];
            float a = v00 * (1.f - wy) + v10 * wy;
            float b = v01 * (1.f - wy) + v11 * wy;
            two[e] = f2bf(a * (1.f - wx) + b * wx);
        }
        d[q4] = two[0] | (two[1] << 16);
    }
    uint4 v = {d[0], d[1], d[2], d[3]};
    *(uint4*)(upT + ((size_t)y * W + x) * 64 + cg * 8) = v;
}

// ---------------- img cvt: i1,i2 [4][3][306][306] f32 -> imgb [2][4][3][306][312] bf16 (pad=0)
__global__ void img_cvt(const float* __restrict__ i1, const float* __restrict__ i2,
                        uint16_t* __restrict__ dst) {
    int task = blockIdx.x * 256 + threadIdx.x;      // 7344 rows x 39 chunks
    if (task >= 7344 * 39) return;
    int ch8 = task % 39, row = task / 39;
    int u0 = ch8 * 8;
    int img = row / 3672;
    int r = row - img * 3672;
    const float* src = (img ? i2 : i1) + (size_t)r * WIMG;
    uint32_t d[4];
#pragma unroll
    for (int p = 0; p < 4; ++p) {
        int u = u0 + p * 2;
        uint32_t lo = (u < WIMG) ? f2bf(src[u]) : 0u;
        uint32_t hi = (u + 1 < WIMG) ? f2bf(src[u + 1]) : 0u;
        d[p] = lo | (hi << 16);
    }
    uint4 v = {d[0], d[1], d[2], d[3]};
    *(uint4*)(dst + (size_t)row * IMW + u0) = v;
}

// ---------------- weight prep: [4][51][CIN][3][3] f32 -> A-fragment order bf16 ------
__global__ void wprep(const float* __restrict__ wsrc, uint16_t* __restrict__ wdst, int cin_act) {
    int g = blockIdx.x * 256 + threadIdx.x;    // one per 16B group: 4*9*4*2*64 = 18432
    if (g >= 4 * 9 * 4 * 2 * 64) return;
    int lane = g & 63;
    int q = g >> 6;
    int ch = q & 1; q >>= 1;
    int m = q & 3; q >>= 2;
    int tap = q % 9;
    int k = q / 9;
    int co = m * 16 + (lane & 15);
    int ci0 = ch * 32 + (lane >> 4) * 8;
    uint32_t d[4];
#pragma unroll
    for (int p = 0; p < 4; ++p) {
        uint32_t w2[2];
#pragma unroll
        for (int e = 0; e < 2; ++e) {
            int ci = ci0 + p * 2 + e;
            float v = 0.f;
            if (co < KK && ci < cin_act)
                v = wsrc[((size_t)(k * KK + co) * cin_act + ci) * 9 + tap];
            w2[e] = f2bf(v);
        }
        d[p] = w2[0] | (w2[1] << 16);
    }
    uint4 v = {d[0], d[1], d[2], d[3]};
    *(uint4*)(wdst + (size_t)g * 8) = v;
}

// ---------------- MFMA conv 3x3 + bias + relu, LDS-bounce coalesced epilogue --------
__global__ __launch_bounds__(256, 2)
void conv_mfma(const uint16_t* __restrict__ in, const uint16_t* __restrict__ wp,
               const float* __restrict__ bias, uint16_t* __restrict__ out,
               size_t in_kstride, int kbase) {
    const int z = blockIdx.z;
    const int k = kbase + z;
    in  += (size_t)z * in_kstride;
    out += (size_t)z * CHAIN;
    const int y0 = blockIdx.x * 4;
    const int x0 = blockIdx.y * 128;
    const int tid = threadIdx.x;
    const int lane = tid & 63;
    const int wv = tid >> 6;
    const int y = y0 + wv;

    __shared__ uint4 lds[6 * 130 * 4];   // 49920 B; reused as store-bounce tile

    f32x4 acc[4][8];
#pragma unroll
    for (int m = 0; m < 4; ++m)
#pragma unroll
        for (int n = 0; n < 8; ++n)
            acc[m][n] = (f32x4){0.f, 0.f, 0.f, 0.f};

    for (int chf = 0; chf < 2; ++chf) {
        if (chf) __syncthreads();
        for (int task = tid; task < 6 * 130 * 4; task += 256) {
            int chunk = task & 3;
            int xl = (task >> 2) % 130;
            int r = (task >> 2) / 130;
            int yg = y0 - 1 + r;
            int xg = x0 + xl - 1;
            uint4 v = {0u, 0u, 0u, 0u};
            if ((unsigned)yg < H && (unsigned)xg < W)
                v = *(const uint4*)(in + (((size_t)yg * W + xg) * 64 + chf * 32 + chunk * 8));
            int slot = chunk ^ ((xl >> 1) & 3);
            lds[(r * 130 + xl) * 4 + slot] = v;
        }
        __syncthreads();

#pragma unroll
        for (int tap = 0; tap < 9; ++tap) {
            const int ky = tap / 3, kx = tap % 3;
            bhalf8 afr[4];
#pragma unroll
            for (int m = 0; m < 4; ++m)
                afr[m] = *(const bhalf8*)(wp + ((((size_t)(k * 9 + tap) * 4 + m) * 2 + chf) * 64 + lane) * 8);
            const int rrow = wv + ky;
            const int chunk = lane >> 4;
#pragma unroll
            for (int n = 0; n < 8; ++n) {
                int xl = n * 16 + (lane & 15) + kx;
                int slot = chunk ^ ((xl >> 1) & 3);
                bhalf8 bfr = *(const bhalf8*)&lds[(rrow * 130 + xl) * 4 + slot];
#pragma unroll
                for (int m = 0; m < 4; ++m)
                    acc[m][n] = __builtin_amdgcn_mfma_f32_16x16x32_bf16(afr[m], bfr, acc[m][n], 0, 0, 0);
            }
        }
    }

    // ---- epilogue: bias+relu+pack -> per-wave LDS [64x][64co] tile -> coalesced stores
    __syncthreads();                          // all waves done reading staged B
    const int colx = lane & 15;
    const int r4 = lane >> 4;
    ushort* ST = (ushort*)lds + wv * 4096;    // 8 KB per wave, 32 KB total
    float bv[4][4];
#pragma unroll
    for (int m = 0; m < 4; ++m)
#pragma unroll
        for (int r = 0; r < 4; ++r) {
            int co = m * 16 + r4 * 4 + r;
            bv[m][r] = (co < KK) ? bias[k * KK + co] : 0.f;
        }

#pragma unroll
    for (int ph = 0; ph < 2; ++ph) {
#pragma unroll
        for (int m = 0; m < 4; ++m) {
#pragma unroll
            for (int nn = 0; nn < 4; ++nn) {
                int n = ph * 4 + nn;
                int xl = nn * 16 + colx;
                uint32_t pk[2];
#pragma unroll
                for (int hh = 0; hh < 2; ++hh) {
                    uint32_t lo = f2bf(fmaxf(acc[m][n][hh * 2]     + bv[m][hh * 2],     0.f));
                    uint32_t hi = f2bf(fmaxf(acc[m][n][hh * 2 + 1] + bv[m][hh * 2 + 1], 0.f));
                    pk[hh] = lo | (hi << 16);
                }
                int co0 = m * 16 + r4 * 4;
                int idx = xl * 64 + (co0 ^ ((xl & 7) << 3));   // XOR swizzle, 8B-contig
                *(uint2*)(ST + idx) = (uint2){pk[0], pk[1]};
            }
        }
        const int p8 = lane >> 3;
        const int chunk = lane & 7;
#pragma unroll
        for (int it = 0; it < 8; ++it) {
            int px = it * 8 + p8;
            uint4 v = *(const uint4*)(ST + px * 64 + ((chunk ^ (px & 7)) << 3));
            int xg = x0 + ph * 64 + px;
            *(uint4*)(out + (((size_t)y * W + xg) * 64 + chunk * 8)) = v;
        }
    }
}

// ---------------- sepconv via MFMA band-matmul -------------------------------------
__global__ __launch_bounds__(256, 2)
void sepconv3(const uint16_t* __restrict__ imgb,
              const uint16_t* __restrict__ kvT, const uint16_t* __restrict__ khT,
              float* __restrict__ out, int accum) {
    __shared__ uint4 SB[320 * 8];
    __shared__ float SC[4][16 * 83];
    const int y = blockIdx.x, c = blockIdx.y;
    const int tid = threadIdx.x, lane = tid & 63, wv = tid >> 6;
    const uint16_t* img = imgb + (size_t)c * HIMG * IMW;

    for (int task = tid; task < 40 * 64; task += 256) {
        int i = task & 63;
        int u0 = (task >> 6) * 8;
        uint4 v = {0u, 0u, 0u, 0u};
        if (i <= 50 && u0 < IMW)
            v = *(const uint4*)(img + (size_t)(y + i) * IMW + u0);
        ushort* vs = (ushort*)&v;
#pragma unroll
        for (int e = 0; e < 8; ++e) {
            int u = u0 + e;
            *((ushort*)SB + u * 64 + (((i >> 3) ^ (u & 7)) << 3) + (i & 7)) = vs[e];
        }
    }
    __syncthreads();

    const int l4 = lane & 15, g = lane >> 4;
    for (int xt = 0; xt < 4; ++xt) {
        const int x0 = (wv * 4 + xt) * 16;
        const int xpix = x0 + l4;
        bhalf8 a0 = *(const bhalf8*)(kvT + ((size_t)y * W + xpix) * 64 + g * 8);
        bhalf8 a1 = *(const bhalf8*)(kvT + ((size_t)y * W + xpix) * 64 + 32 + g * 8);
        f32x4 acc[5];
#pragma unroll
        for (int nt = 0; nt < 5; ++nt) acc[nt] = (f32x4){0.f, 0.f, 0.f, 0.f};
#pragma unroll
        for (int nt = 0; nt < 5; ++nt) {
            int u = x0 + nt * 16 + l4;
            bhalf8 b0 = *(const bhalf8*)((ushort*)SB + u * 64 + ((g ^ (u & 7)) << 3));
            acc[nt] = __builtin_amdgcn_mfma_f32_16x16x32_bf16(a0, b0, acc[nt], 0, 0, 0);
            bhalf8 b1 = *(const bhalf8*)((ushort*)SB + u * 64 + (((4 + g) ^ (u & 7)) << 3));
            acc[nt] = __builtin_amdgcn_mfma_f32_16x16x32_bf16(a1, b1, acc[nt], 0, 0, 0);
        }
#pragma unroll
        for (int nt = 0; nt < 5; ++nt)
#pragma unroll
            for (int r = 0; r < 4; ++r)
                SC[wv][(g * 4 + r) * 83 + nt * 16 + l4] = acc[nt][r];

        const uint16_t* khp = khT + ((size_t)y * W + xpix) * 64;
        float partial = 0.f;
#pragma unroll
        for (int jj = 0; jj < 13; ++jj) {
            int j = g * 13 + jj;
            if (j < KK)
                partial = fmaf(SC[wv][l4 * 83 + l4 + j], bf2f(khp[j]), partial);
        }
        partial += __shfl_xor(partial, 16);
        partial += __shfl_xor(partial, 32);
        if (g == 0) {
            size_t oi = ((size_t)c * H + y) * W + xpix;
            if (accum) out[oi] += partial;
            else       out[oi] = partial;
        }
    }
}

extern "C" void kernel_launch(void* const* d_in, const int* in_sizes, int n_in,
                              void* d_out, int out_size, void* d_ws, size_t ws_size,
                              hipStream_t stream) {
    const float* x  = (const float*)d_in[0];
    const float* i1 = (const float*)d_in[1];
    const float* i2 = (const float*)d_in[2];
    const float* W1 = (const float*)d_in[3];
    const float* B1 = (const float*)d_in[4];
    const float* W2 = (const float*)d_in[5];
    const float* B2 = (const float*)d_in[6];
    const float* W3 = (const float*)d_in[7];
    const float* B3 = (const float*)d_in[8];
    float* out = (float*)d_out;

    char* wsb = (char*)d_ws;
    const size_t IMGB = CHAIN * 2;
    const size_t WPN  = 4 * 9 * 4 * 2 * 64 * 8;
    const size_t WPB  = WPN * 2;
    const size_t IMGBYTES = (size_t)2 * 4 * 3 * HIMG * IMW * 2;
    const size_t FULL_NEED = 13 * IMGB + 3 * WPB + IMGBYTES;
    const bool full = ws_size >= FULL_NEED;
    const int IMG_CVT_BLOCKS = (7344 * 39 + 255) / 256;

    if (full) {
        uint16_t* r1   = (uint16_t*)wsb;
        uint16_t* r2   = (uint16_t*)(wsb + 4 * IMGB);
        uint16_t* r3   = (uint16_t*)(wsb + 8 * IMGB);
        uint16_t* upT  = (uint16_t*)(wsb + 12 * IMGB);
        uint16_t* wp1  = (uint16_t*)(wsb + 13 * IMGB);
        uint16_t* wp2  = wp1 + WPN;
        uint16_t* wp3  = wp2 + WPN;
        uint16_t* imgb = wp3 + WPN;

        wprep<<<72, 256, 0, stream>>>(W1, wp1, CF);
        wprep<<<72, 256, 0, stream>>>(W2, wp2, KK);
        wprep<<<72, 256, 0, stream>>>(W3, wp3, KK);
        img_cvt<<<IMG_CVT_BLOCKS, 256, 0, stream>>>(i1, i2, imgb);

        for (int b = 0; b < BB; ++b) {
            upsample_cvt<<<dim3(H, 8), 256, 0, stream>>>(x + (size_t)b * CF * HH * HH, upT);
            conv_mfma<<<dim3(64, 2, 4), 256, 0, stream>>>(upT, wp1, B1, r1, 0, 0);
            conv_mfma<<<dim3(64, 2, 4), 256, 0, stream>>>(r1, wp2, B2, r2, CHAIN, 0);
            conv_mfma<<<dim3(64, 2, 4), 256, 0, stream>>>(r2, wp3, B3, r3, CHAIN, 0);
            for (int p = 0; p < 2; ++p) {
                const uint16_t* ib = imgb + ((size_t)(p * 12 + b * 3) * HIMG) * IMW;
                sepconv3<<<dim3(H, 3), 256, 0, stream>>>(ib,
                        r3 + (size_t)(2 * p) * CHAIN, r3 + (size_t)(2 * p + 1) * CHAIN,
                        out + (size_t)b * 3 * HWN, p);
            }
        }
    } else {
        uint16_t* upT  = (uint16_t*)wsb;
        uint16_t* t1   = (uint16_t*)(wsb + 1 * IMGB);
        uint16_t* t2   = (uint16_t*)(wsb + 3 * IMGB);
        uint16_t* t3   = (uint16_t*)(wsb + 5 * IMGB);
        uint16_t* wp1  = (uint16_t*)(wsb + 7 * IMGB);
        uint16_t* wp2  = wp1 + WPN;
        uint16_t* wp3  = wp2 + WPN;
        uint16_t* imgb = wp3 + WPN;

        wprep<<<72, 256, 0, stream>>>(W1, wp1, CF);
        wprep<<<72, 256, 0, stream>>>(W2, wp2, KK);
        wprep<<<72, 256, 0, stream>>>(W3, wp3, KK);
        img_cvt<<<IMG_CVT_BLOCKS, 256, 0, stream>>>(i1, i2, imgb);

        for (int b = 0; b < BB; ++b) {
            upsample_cvt<<<dim3(H, 8), 256, 0, stream>>>(x + (size_t)b * CF * HH * HH, upT);
            for (int p = 0; p < 2; ++p) {
                conv_mfma<<<dim3(64, 2, 2), 256, 0, stream>>>(upT, wp1, B1, t1, 0, 2 * p);
                conv_mfma<<<dim3(64, 2, 2), 256, 0, stream>>>(t1, wp2, B2, t2, CHAIN, 2 * p);
                conv_mfma<<<dim3(64, 2, 2), 256, 0, stream>>>(t2, wp3, B3, t3, CHAIN, 2 * p);
                const uint16_t* ib = imgb + ((size_t)(p * 12 + b * 3) * HIMG) * IMW;
                sepconv3<<<dim3(H, 3), 256, 0, stream>>>(ib, t3, t3 + CHAIN,
                        out + (size_t)b * 3 * HWN, p);
            }
        }
    }
}